// Round 4
// baseline (45.191 us; speedup 1.0000x reference)
//
#include <hip/hip_runtime.h>

#define DIM 64

__device__ __forceinline__ void f4acc(float4& a, const float4& v) {
    a.x += v.x; a.y += v.y; a.z += v.z; a.w += v.w;
}

// lower_bound(seg, key) over sorted seg[0..n), seeded with a position guess.
// Gallops outward from the guess to bracket the target, then binary-searches.
// Correct for any sorted input; fast (~O(log distance)) when guess is close.
__device__ __forceinline__ int lower_bound_gallop(
    const int* __restrict__ seg, int n, int key, int guess)
{
    if (guess < 0) guess = 0;
    if (guess > n) guess = n;
    int lo, hi;
    if (guess >= n || seg[guess] >= key) {
        // target <= guess: gallop left. invariant: seg[hi] >= key (target <= hi)
        hi = guess;
        int step = 256;
        lo = 0;
        for (;;) {
            int probe = hi - step;
            if (probe <= 0) { lo = 0; break; }
            if (seg[probe] >= key) { hi = probe; step <<= 1; }
            else { lo = probe + 1; break; }
        }
    } else {
        // seg[guess] < key: gallop right. invariant: seg[lo-1] < key
        lo = guess + 1;
        hi = n;
        int step = 256;
        for (;;) {
            int probe = lo + step;
            if (probe >= n) { hi = n; break; }
            if (seg[probe] < key) { lo = probe + 1; step <<= 1; }
            else { hi = probe; break; }
        }
    }
    while (lo < hi) {
        int mid = (lo + hi) >> 1;
        if (seg[mid] < key) lo = mid + 1; else hi = mid;
    }
    return lo;
}

// Gather + segment-sum, fully fused. One wave per segment.
// Lane layout: sub = lane>>4 picks the row within a group of 4, col4 = lane&15
// picks the float4 column. One gather instruction = 64 lanes x 16B = 4 full rows.
// ids for a 64-row chunk are preloaded with ONE coalesced lane-indexed load and
// redistributed via __shfl, keeping global ids loads off the gather critical path.
__global__ __launch_bounds__(256) void emb_seg_sum_kernel(
    const float* __restrict__ params,
    const int*   __restrict__ ids,
    const int*   __restrict__ seg,
    float*       __restrict__ out,
    int n_ids, int num_segments)
{
    const int gtid = blockIdx.x * blockDim.x + threadIdx.x;
    const int wseg = gtid >> 6;
    const int lane = threadIdx.x & 63;
    if (wseg >= num_segments) return;

    const int avg = n_ids / num_segments;
    const int guess = (int)(((long long)wseg * n_ids) / num_segments);
    const int start = lower_bound_gallop(seg, n_ids, wseg, guess);
    const int end   = lower_bound_gallop(seg, n_ids, wseg + 1, start + avg);

    const int sub  = lane >> 4;              // row within group-of-4
    const int col4 = lane & 15;              // float4 column
    const float* __restrict__ pcol = params + col4 * 4;

    float4 a0 = {0,0,0,0}, a1 = {0,0,0,0}, a2 = {0,0,0,0}, a3 = {0,0,0,0};

    for (int base = start; base < end; base += 64) {
        const int cnt = min(64, end - base);
        // One coalesced load covers this chunk's ids.
        int myid = 0;
        if (base + lane < end) myid = ids[base + lane];

        int j = 0;
        for (; j + 16 <= cnt; j += 16) {
            const int i0 = __shfl(myid, j      + sub);
            const int i1 = __shfl(myid, j + 4  + sub);
            const int i2 = __shfl(myid, j + 8  + sub);
            const int i3 = __shfl(myid, j + 12 + sub);
            const float4 v0 = *(const float4*)(pcol + (size_t)i0 * DIM);
            const float4 v1 = *(const float4*)(pcol + (size_t)i1 * DIM);
            const float4 v2 = *(const float4*)(pcol + (size_t)i2 * DIM);
            const float4 v3 = *(const float4*)(pcol + (size_t)i3 * DIM);
            f4acc(a0, v0); f4acc(a1, v1); f4acc(a2, v2); f4acc(a3, v3);
        }
        for (; j + 4 <= cnt; j += 4) {
            const int i0 = __shfl(myid, j + sub);
            f4acc(a1, *(const float4*)(pcol + (size_t)i0 * DIM));
        }
        if (j < cnt) {
            const int r  = j + sub;
            const int i0 = __shfl(myid, (r < cnt) ? r : j);
            if (r < cnt) {
                f4acc(a2, *(const float4*)(pcol + (size_t)i0 * DIM));
            }
        }
    }

    f4acc(a0, a1); f4acc(a2, a3); f4acc(a0, a2);

    // Reduce across the 4 row-subsets (lane bits 4 and 5).
    a0.x += __shfl_xor(a0.x, 16); a0.y += __shfl_xor(a0.y, 16);
    a0.z += __shfl_xor(a0.z, 16); a0.w += __shfl_xor(a0.w, 16);
    a0.x += __shfl_xor(a0.x, 32); a0.y += __shfl_xor(a0.y, 32);
    a0.z += __shfl_xor(a0.z, 32); a0.w += __shfl_xor(a0.w, 32);

    if (lane < 16) {
        *(float4*)(out + (size_t)wseg * DIM + col4 * 4) = a0;
    }
}

extern "C" void kernel_launch(void* const* d_in, const int* in_sizes, int n_in,
                              void* d_out, int out_size, void* d_ws, size_t ws_size,
                              hipStream_t stream)
{
    const float* params = (const float*)d_in[0];
    const int*   ids    = (const int*)d_in[1];
    const int*   seg    = (const int*)d_in[2];
    float*       out    = (float*)d_out;

    const int n_ids        = in_sizes[1];
    const int num_segments = out_size / DIM;

    const int threads = 256;                        // 4 waves per block
    const int waves_per_block = threads / 64;
    const int grid = (num_segments + waves_per_block - 1) / waves_per_block;

    emb_seg_sum_kernel<<<grid, threads, 0, stream>>>(
        params, ids, seg, out, n_ids, num_segments);
}

// Round 5
// 43.754 us; speedup vs baseline: 1.0328x; 1.0328x over previous
//
#include <hip/hip_runtime.h>

#define DIM 64

__device__ __forceinline__ void f4acc(float4& a, const float4& v) {
    a.x += v.x; a.y += v.y; a.z += v.z; a.w += v.w;
}

// Chunk-per-wave segment-sum over sorted (ids, segment_ids).
// Each wave owns 64 consecutive ids: one coalesced load of ids + seg, run
// boundaries via ballot. Interior runs (segment fully inside the chunk) get a
// plain store; edge runs (first/last run of the chunk, possibly shared with a
// neighboring chunk) get atomicAdd. Output must be pre-zeroed (memset in
// kernel_launch). Gather layout: sub = lane>>4 picks the row within a group
// of 4, col4 = lane&15 picks the float4 column -> one gather instruction
// covers 4 full 256B rows.
__global__ __launch_bounds__(256) void emb_chunk_seg_sum_kernel(
    const float* __restrict__ params,
    const int*   __restrict__ ids,
    const int*   __restrict__ seg,
    float*       __restrict__ out,
    int n_ids)
{
    const int gtid = blockIdx.x * blockDim.x + threadIdx.x;
    const int wave = gtid >> 6;
    const int lane = threadIdx.x & 63;
    const int base = wave << 6;
    if (base >= n_ids) return;
    const int cnt = min(64, n_ids - base);

    int myid  = 0;
    int myseg = 0x7FFFFFFF;                 // sentinel for pad lanes
    if (lane < cnt) {
        myid  = ids[base + lane];
        myseg = seg[base + lane];
    }

    // Run-head mask: lane l starts a new run iff seg changes at l.
    const int prevseg = __shfl_up(myseg, 1);   // lane 0 keeps its own
    const bool head = (lane < cnt) && (lane == 0 || prevseg != myseg);
    unsigned long long hm = __ballot(head);

    const int sub  = lane >> 4;             // row within group-of-4
    const int col4 = lane & 15;             // float4 column
    const float* __restrict__ pcol = params + col4 * 4;

    unsigned long long m = hm;
    while (m) {
        const int s = __ffsll(m) - 1;       // run start (wave-uniform)
        m &= m - 1;
        const int e = m ? (__ffsll(m) - 1) : cnt;   // run end
        const int segid = __shfl(myseg, s);

        float4 a0 = {0,0,0,0}, a1 = {0,0,0,0};
        int j = s;
        for (; j + 8 <= e; j += 8) {
            const int i0 = __shfl(myid, j     + sub);
            const int i1 = __shfl(myid, j + 4 + sub);
            const float4 v0 = *(const float4*)(pcol + (size_t)i0 * DIM);
            const float4 v1 = *(const float4*)(pcol + (size_t)i1 * DIM);
            f4acc(a0, v0); f4acc(a1, v1);
        }
        for (; j + 4 <= e; j += 4) {
            const int i0 = __shfl(myid, j + sub);
            f4acc(a0, *(const float4*)(pcol + (size_t)i0 * DIM));
        }
        if (j < e) {
            const int r  = j + sub;
            const int i0 = __shfl(myid, (r < e) ? r : j);
            if (r < e) {
                f4acc(a1, *(const float4*)(pcol + (size_t)i0 * DIM));
            }
        }
        f4acc(a0, a1);

        // Combine the 4 row-subsets (lane bits 4 and 5). All lanes end up
        // holding the run total for their col4.
        a0.x += __shfl_xor(a0.x, 16); a0.y += __shfl_xor(a0.y, 16);
        a0.z += __shfl_xor(a0.z, 16); a0.w += __shfl_xor(a0.w, 16);
        a0.x += __shfl_xor(a0.x, 32); a0.y += __shfl_xor(a0.y, 32);
        a0.z += __shfl_xor(a0.z, 32); a0.w += __shfl_xor(a0.w, 32);

        const bool edge = (s == 0) || (e == cnt);
        if (edge) {
            // Spread 64 dims across 64 lanes: dim `lane` lives in component
            // (lane&3) of the float4 held at col4 = lane>>2.
            const float ax = __shfl(a0.x, lane >> 2);
            const float ay = __shfl(a0.y, lane >> 2);
            const float az = __shfl(a0.z, lane >> 2);
            const float aw = __shfl(a0.w, lane >> 2);
            const float v  = (lane & 2) ? ((lane & 1) ? aw : az)
                                        : ((lane & 1) ? ay : ax);
            atomicAdd(out + (size_t)segid * DIM + lane, v);
        } else {
            // Segment is exclusive to this chunk: plain store over the zeros.
            if (lane < 16) {
                *(float4*)(out + (size_t)segid * DIM + col4 * 4) = a0;
            }
        }
    }
}

extern "C" void kernel_launch(void* const* d_in, const int* in_sizes, int n_in,
                              void* d_out, int out_size, void* d_ws, size_t ws_size,
                              hipStream_t stream)
{
    const float* params = (const float*)d_in[0];
    const int*   ids    = (const int*)d_in[1];
    const int*   seg    = (const int*)d_in[2];
    float*       out    = (float*)d_out;

    const int n_ids = in_sizes[1];

    // Zero the output (poisoned by harness; empty segments must read 0).
    hipMemsetAsync(out, 0, (size_t)out_size * sizeof(float), stream);

    const int nwaves  = (n_ids + 63) / 64;
    const int threads = 256;                       // 4 waves per block
    const int grid    = (nwaves + 3) / 4;

    emb_chunk_seg_sum_kernel<<<grid, threads, 0, stream>>>(
        params, ids, seg, out, n_ids);
}

// Round 6
// 42.303 us; speedup vs baseline: 1.0683x; 1.0343x over previous
//
#include <hip/hip_runtime.h>

#define DIM 64

__device__ __forceinline__ void f4acc(float4& a, const float4& v) {
    a.x += v.x; a.y += v.y; a.z += v.z; a.w += v.w;
}

// Kernel 1: offsets[s] = lower_bound(seg, s) for s in [0, num_segments].
// segment_ids is sorted, so each thread i marks the boundary gap (seg[i-1], seg[i]].
__global__ void seg_offsets_kernel(const int* __restrict__ seg, int* __restrict__ offsets,
                                   int n_ids, int num_segments)
{
    int i = blockIdx.x * blockDim.x + threadIdx.x;
    if (i >= n_ids) return;
    int cur  = seg[i];
    int prev = (i == 0) ? -1 : seg[i - 1];
    for (int s = prev + 1; s <= cur; ++s) offsets[s] = i;
    if (i == n_ids - 1) {
        for (int s = cur + 1; s <= num_segments; ++s) offsets[s] = n_ids;
    }
}

// Gather + segment-sum. One wave per segment.
// Lane layout: sub = lane>>4 picks the row within a group of 4, col4 = lane&15
// picks the float4 column. One gather instruction = 64 lanes x 16B = 4 full rows.
// ids for the segment are preloaded with ONE coalesced lane-indexed load and
// redistributed via __shfl, keeping global ids loads off the gather critical path.
template <bool USE_OFFSETS>
__global__ __launch_bounds__(256) void emb_seg_sum_kernel(
    const float* __restrict__ params,
    const int*   __restrict__ ids,
    const int*   __restrict__ seg_or_off,
    float*       __restrict__ out,
    int n_ids, int num_segments)
{
    const int gtid = blockIdx.x * blockDim.x + threadIdx.x;
    const int wseg = gtid >> 6;
    const int lane = threadIdx.x & 63;
    if (wseg >= num_segments) return;

    int start, end;
    if (USE_OFFSETS) {
        start = seg_or_off[wseg];
        end   = seg_or_off[wseg + 1];
    } else {
        int lo = 0, hi = n_ids;
        while (lo < hi) {
            int mid = (lo + hi) >> 1;
            if (seg_or_off[mid] < wseg) lo = mid + 1; else hi = mid;
        }
        start = lo;
        hi = n_ids;
        while (lo < hi) {
            int mid = (lo + hi) >> 1;
            if (seg_or_off[mid] <= wseg) lo = mid + 1; else hi = mid;
        }
        end = lo;
    }

    const int sub  = lane >> 4;              // row within group-of-4
    const int col4 = lane & 15;              // float4 column
    const float* __restrict__ pcol = params + col4 * 4;

    float4 a0 = {0,0,0,0}, a1 = {0,0,0,0}, a2 = {0,0,0,0}, a3 = {0,0,0,0};

    for (int base = start; base < end; base += 64) {
        const int cnt = min(64, end - base);
        // One coalesced load covers this chunk's ids.
        int myid = 0;
        if (base + lane < end) myid = ids[base + lane];

        int j = 0;
        for (; j + 16 <= cnt; j += 16) {
            const int i0 = __shfl(myid, j      + sub);
            const int i1 = __shfl(myid, j + 4  + sub);
            const int i2 = __shfl(myid, j + 8  + sub);
            const int i3 = __shfl(myid, j + 12 + sub);
            const float4 v0 = *(const float4*)(pcol + (size_t)i0 * DIM);
            const float4 v1 = *(const float4*)(pcol + (size_t)i1 * DIM);
            const float4 v2 = *(const float4*)(pcol + (size_t)i2 * DIM);
            const float4 v3 = *(const float4*)(pcol + (size_t)i3 * DIM);
            f4acc(a0, v0); f4acc(a1, v1); f4acc(a2, v2); f4acc(a3, v3);
        }
        for (; j + 4 <= cnt; j += 4) {
            const int i0 = __shfl(myid, j + sub);
            f4acc(a1, *(const float4*)(pcol + (size_t)i0 * DIM));
        }
        if (j < cnt) {
            const int r  = j + sub;
            const int i0 = __shfl(myid, (r < cnt) ? r : j);
            if (r < cnt) {
                f4acc(a2, *(const float4*)(pcol + (size_t)i0 * DIM));
            }
        }
    }

    f4acc(a0, a1); f4acc(a2, a3); f4acc(a0, a2);

    // Reduce across the 4 row-subsets (lane bits 4 and 5).
    a0.x += __shfl_xor(a0.x, 16); a0.y += __shfl_xor(a0.y, 16);
    a0.z += __shfl_xor(a0.z, 16); a0.w += __shfl_xor(a0.w, 16);
    a0.x += __shfl_xor(a0.x, 32); a0.y += __shfl_xor(a0.y, 32);
    a0.z += __shfl_xor(a0.z, 32); a0.w += __shfl_xor(a0.w, 32);

    if (lane < 16) {
        *(float4*)(out + (size_t)wseg * DIM + col4 * 4) = a0;
    }
}

extern "C" void kernel_launch(void* const* d_in, const int* in_sizes, int n_in,
                              void* d_out, int out_size, void* d_ws, size_t ws_size,
                              hipStream_t stream)
{
    const float* params = (const float*)d_in[0];
    const int*   ids    = (const int*)d_in[1];
    const int*   seg    = (const int*)d_in[2];
    float*       out    = (float*)d_out;

    const int n_ids        = in_sizes[1];
    const int num_segments = out_size / DIM;

    const int threads = 256;                        // 4 waves per block
    const int waves_per_block = threads / 64;
    const int grid = (num_segments + waves_per_block - 1) / waves_per_block;

    const size_t off_bytes = (size_t)(num_segments + 1) * sizeof(int);
    if (ws_size >= off_bytes) {
        int* offsets = (int*)d_ws;
        seg_offsets_kernel<<<(n_ids + 255) / 256, 256, 0, stream>>>(
            seg, offsets, n_ids, num_segments);
        emb_seg_sum_kernel<true><<<grid, threads, 0, stream>>>(
            params, ids, offsets, out, n_ids, num_segments);
    } else {
        emb_seg_sum_kernel<false><<<grid, threads, 0, stream>>>(
            params, ids, seg, out, n_ids, num_segments);
    }
}